// Round 1
// baseline (1880.640 us; speedup 1.0000x reference)
//
#include <hip/hip_runtime.h>

// PerturbationAttention: delta [B=2048, C=512, D=256] f32, k=256.
// sigma = ||delta||_2 over D; att = tanh(1 - sigma/max(sigma)); softmax over C;
// zero the k smallest att per row (stable ties -> lower index zeroed first).
//
// Correctness strategy: selection must match the numpy reference EXACTLY
// (threshold = 2% of max => any wrong top-k element fails). We make sigma
// bit-exact by replicating numpy's pairwise-summation order for n=256
// (identity-init: P(0:128)+P(128:256), each via 8 strided accumulators and
// the ((r0+r1)+(r2+r3))+((r4+r5)+(r6+r7)) combine), with FMA contraction off.
// x = 1 - sigma/gmax is then bit-identical (CR div, Sterbenz-exact subtract);
// tanh/exp/softmax are monotone, so ranking by (x asc, idx asc) reproduces
// top_k(-att) tie-for-tie except downstream rounding-created ties (rare).

#define DDIM 256
#define CDIM 512

__global__ __launch_bounds__(256) void k_sigma(const float* __restrict__ delta,
                                               float* __restrict__ sigma,
                                               unsigned int* __restrict__ gmax_bits) {
#pragma clang fp contract(off)
    const int lane        = threadIdx.x & 63;
    const int waveInBlock = threadIdx.x >> 6;
    const int rw  = lane >> 4;        // row within wave: 0..3
    const int sub = lane & 15;        // 0..15: (half, acc-j)
    const int h   = sub >> 3;         // 128-element half
    const int j   = sub & 7;          // numpy accumulator index
    const int row = (blockIdx.x * 4 + waveInBlock) * 4 + rw;

    const float* p = delta + (size_t)row * DDIM + h * 128 + j;
    // r_j = sq[j] + sq[j+8] + ... + sq[j+120], sequential (numpy order)
    float y0 = p[0];
    float r  = y0 * y0;
#pragma unroll
    for (int t = 1; t < 16; ++t) {
        float y  = p[8 * t];
        float sq = y * y;        // separate mul+add (contract off) = numpy
        r = r + sq;
    }
    // combine tree ((r0+r1)+(r2+r3))+((r4+r5)+(r6+r7)) == xor-1,2,4 butterfly
    r = r + __shfl_xor(r, 1);
    r = r + __shfl_xor(r, 2);
    r = r + __shfl_xor(r, 4);
    // total = P(first 128) + P(second 128)
    r = r + __shfl_xor(r, 8);
    float sig = sqrtf(r);        // CR on both sides
    if (sub == 0) sigma[row] = sig;

    // global max (exact regardless of order): block-reduce then one atomic
    float m = fmaxf(sig, __shfl_xor(sig, 16));
    m = fmaxf(m, __shfl_xor(m, 32));
    __shared__ float wmax[4];
    if (lane == 0) wmax[waveInBlock] = m;
    __syncthreads();
    if (threadIdx.x == 0) {
        float bm = fmaxf(fmaxf(wmax[0], wmax[1]), fmaxf(wmax[2], wmax[3]));
        atomicMax(gmax_bits, __float_as_uint(bm));   // sig >= 0: uint-order ok
    }
}

__global__ __launch_bounds__(512) void k_attn(float* __restrict__ out,  // in: sigma, out: att
                                              const unsigned int* __restrict__ gmax_bits,
                                              const int* __restrict__ kptr) {
    const int b = blockIdx.x;
    const int c = threadIdx.x;   // 0..511
    __shared__ float s_x[CDIM];
    __shared__ float s_red[8];

    const float gmax = __uint_as_float(*gmax_bits);
    const int   k    = *kptr;

    float sig = out[(size_t)b * CDIM + c];
    float s   = sig / gmax;          // CR div: bit-identical to ref
    float x   = 1.0f - s;            // Sterbenz-exact for s in [0.5, 1]
    s_x[c] = x;

    float t = tanhf(x);
    float e = expf(t);

    // block sum of e (value-only; 4.6e-5 slack is huge vs ~3e-7 rel err)
    float sum = e;
#pragma unroll
    for (int off = 1; off < 64; off <<= 1) sum += __shfl_xor(sum, off);
    if ((threadIdx.x & 63) == 0) s_red[threadIdx.x >> 6] = sum;
    __syncthreads();
    float tot = ((s_red[0] + s_red[1]) + (s_red[2] + s_red[3])) +
                ((s_red[4] + s_red[5]) + (s_red[6] + s_red[7]));

    // stable ascending rank of x: #{x'<x} + #{x'==x && c'<c}
    int cnt = 0;
    for (int cc = 0; cc < c; ++cc)     cnt += (s_x[cc] <= x) ? 1 : 0;
    for (int cc = c; cc < CDIM; ++cc)  cnt += (s_x[cc] <  x) ? 1 : 0;

    float att = e / tot;
    out[(size_t)b * CDIM + c] = (cnt < k) ? 0.0f : att;
}

extern "C" void kernel_launch(void* const* d_in, const int* in_sizes, int n_in,
                              void* d_out, int out_size, void* d_ws, size_t ws_size,
                              hipStream_t stream) {
    const float* delta = (const float*)d_in[0];
    const int*   kptr  = (const int*)d_in[1];
    float*       out   = (float*)d_out;                 // B*C floats
    unsigned int* gmax_bits = (unsigned int*)d_ws;      // 4 bytes used

    const int nrows = out_size;          // B*C = 1048576
    const int B     = nrows / CDIM;      // 2048

    (void)hipMemsetAsync(d_ws, 0, 4, stream);           // gmax := +0.0f
    // K1: 16 rows per 256-thread block (16 lanes/row, numpy-exact reduction)
    k_sigma<<<dim3(nrows / 16), dim3(256), 0, stream>>>(delta, out, gmax_bits);
    // K2: one block per batch row, in-place sigma -> att
    k_attn<<<dim3(B), dim3(CDIM), 0, stream>>>(out, gmax_bits, kptr);
}